// Round 11
// baseline (238.664 us; speedup 1.0000x reference)
//
#include <hip/hip_runtime.h>
#include <cmath>

#define C_DIM 2048
#define B_DIM 16
#define H_DIM 16
#define HS_DIM 128
#define T_DIM 4096
#define ATT_SCALE 0.08838834764831845f  // 1/sqrt(128)
#define TCHUNK 512
#define NCHUNK (T_DIM / TCHUNK)         // 8 blocks per (b,h)

typedef float fx4 __attribute__((ext_vector_type(4)));

__device__ __forceinline__ float4 nt_load4(const float* p) {
  const fx4 r = __builtin_nontemporal_load(reinterpret_cast<const fx4*>(p));
  return make_float4(r.x, r.y, r.z, r.w);
}

// ---------------------------------------------------------------------------
// Kernel 1 & 6: O[16, 2048] = X[16, 2048] @ W[2048, 2048]^T (nt W stream).
// ---------------------------------------------------------------------------
__global__ __launch_bounds__(256) void gemv16_kernel(
    const float* __restrict__ X, const float* __restrict__ W,
    float* __restrict__ O) {
  const int lane = threadIdx.x & 63;
  const int wave = threadIdx.x >> 6;            // 0..3
  const int n = blockIdx.x * 4 + wave;          // output column
  const float* wrow = W + (size_t)n * C_DIM;

  float acc[B_DIM];
#pragma unroll
  for (int m = 0; m < B_DIM; ++m) acc[m] = 0.f;

#pragma unroll
  for (int i = 0; i < C_DIM / 256; ++i) {
    const int j = (i * 64 + lane) * 4;
    const float4 w4 = nt_load4(wrow + j);
#pragma unroll
    for (int m = 0; m < B_DIM; ++m) {
      const float4 x4 = *reinterpret_cast<const float4*>(X + m * C_DIM + j);
      acc[m] += w4.x * x4.x + w4.y * x4.y + w4.z * x4.z + w4.w * x4.w;
    }
  }

#pragma unroll
  for (int m = 0; m < B_DIM; ++m) {
#pragma unroll
    for (int mask = 32; mask >= 1; mask >>= 1)
      acc[m] += __shfl_xor(acc[m], mask, 64);
  }
  if (lane == 0) {
#pragma unroll
    for (int m = 0; m < B_DIM; ++m) O[(size_t)m * C_DIM + n] = acc[m];
  }
}

// ---------------------------------------------------------------------------
// Kernel 2: raw scores. Grid 2048 x 256. Each (wave,half) unit does 4 rows
// per iter (nt k loads) with a TRANSPOSED reduce: 6 shuffles for 4 rows.
// After the reduce, lane class g=dl&3 holds the full sum for row t+8g.
// ---------------------------------------------------------------------------
__global__ __launch_bounds__(256) void attn_scores_kernel(
    const float* __restrict__ q, const float* __restrict__ k,
    float* __restrict__ s) {
  const int blk = blockIdx.x;                   // bh*NCHUNK + chunk
  const int bh = blk >> 3;
  const int chunk = blk & 7;
  const int lane = threadIdx.x & 63;
  const int wave = threadIdx.x >> 6;            // 0..3
  const int half = lane >> 5;
  const int dl = lane & 31;
  const int unit = wave * 2 + half;             // 0..7

  const float* kp = k + (size_t)bh * T_DIM * HS_DIM;
  const float4 qv = reinterpret_cast<const float4*>(q + (size_t)bh * HS_DIM)[dl];
  const int tbase = chunk * TCHUNK + unit;

#pragma unroll 2
  for (int ti = 0; ti < TCHUNK / 32; ++ti) {    // 16 iters, 4 rows/unit/iter
    const size_t t = tbase + (size_t)ti * 32;
    const float4 k0 = nt_load4(kp + (t +  0) * HS_DIM + dl * 4);
    const float4 k1 = nt_load4(kp + (t +  8) * HS_DIM + dl * 4);
    const float4 k2 = nt_load4(kp + (t + 16) * HS_DIM + dl * 4);
    const float4 k3 = nt_load4(kp + (t + 24) * HS_DIM + dl * 4);

    float s0 = k0.x * qv.x + k0.y * qv.y + k0.z * qv.z + k0.w * qv.w;
    float s1 = k1.x * qv.x + k1.y * qv.y + k1.z * qv.z + k1.w * qv.w;
    float s2 = k2.x * qv.x + k2.y * qv.y + k2.z * qv.z + k2.w * qv.w;
    float s3 = k3.x * qv.x + k3.y * qv.y + k3.z * qv.z + k3.w * qv.w;

    // transposed reduce over the 32-lane half-wave (masks stay < 32)
    float a = (dl & 1) ? s0 : s1;               // even sends s1, odd sends s0
    a = __shfl_xor(a, 1, 64);
    const float t01 = ((dl & 1) == 0) ? s0 + a : s1 + a;
    float b = (dl & 1) ? s2 : s3;
    b = __shfl_xor(b, 1, 64);
    const float t23 = ((dl & 1) == 0) ? s2 + b : s3 + b;
    float c = (dl & 2) ? t01 : t23;             // bit1=0 sends t23, keeps t01
    c = __shfl_xor(c, 2, 64);
    float tt = ((dl & 2) == 0) ? t01 + c : t23 + c;
    tt += __shfl_xor(tt, 4, 64);
    tt += __shfl_xor(tt, 8, 64);
    tt += __shfl_xor(tt, 16, 64);
    // lane class g = dl&3 now holds the full 32-lane sum for row t+8g
    if (dl < 4) s[(size_t)bh * T_DIM + t + 8 * dl] = tt * ATT_SCALE;
  }
}

// ---------------------------------------------------------------------------
// Kernel 3: in-place softmax normalize per (b,h): s <- exp(s-m)/L.
// Grid 256 x 256; each thread owns 16 scores in registers.
// ---------------------------------------------------------------------------
__global__ __launch_bounds__(256) void attn_norm_kernel(float* __restrict__ s) {
  const int bh = blockIdx.x;
  const int tid = threadIdx.x;
  const int lane = tid & 63;
  const int wave = tid >> 6;
  float4* sp = reinterpret_cast<float4*>(s + (size_t)bh * T_DIM);

  float4 vv[4];
  float mx = -INFINITY;
#pragma unroll
  for (int i = 0; i < 4; ++i) {
    vv[i] = sp[i * 256 + tid];
    mx = fmaxf(mx, fmaxf(fmaxf(vv[i].x, vv[i].y), fmaxf(vv[i].z, vv[i].w)));
  }
#pragma unroll
  for (int mask = 32; mask >= 1; mask >>= 1)
    mx = fmaxf(mx, __shfl_xor(mx, mask, 64));

  __shared__ float redm[4];
  __shared__ float redl[4];
  if (lane == 0) redm[wave] = mx;
  __syncthreads();
  const float gm = fmaxf(fmaxf(redm[0], redm[1]), fmaxf(redm[2], redm[3]));

  float sum = 0.f;
#pragma unroll
  for (int i = 0; i < 4; ++i) {
    vv[i].x = __expf(vv[i].x - gm);
    vv[i].y = __expf(vv[i].y - gm);
    vv[i].z = __expf(vv[i].z - gm);
    vv[i].w = __expf(vv[i].w - gm);
    sum += vv[i].x + vv[i].y + vv[i].z + vv[i].w;
  }
#pragma unroll
  for (int mask = 32; mask >= 1; mask >>= 1) sum += __shfl_xor(sum, mask, 64);
  if (lane == 0) redl[wave] = sum;
  __syncthreads();
  const float rL = 1.f / (redl[0] + redl[1] + redl[2] + redl[3]);
#pragma unroll
  for (int i = 0; i < 4; ++i) {
    vv[i].x *= rL; vv[i].y *= rL; vv[i].z *= rL; vv[i].w *= rL;
    sp[i * 256 + tid] = vv[i];
  }
}

// ---------------------------------------------------------------------------
// Kernel 4: PV stream. Grid 2048 x 256, same geometry as scores. Pure
// y += p*v: 4 nt v-loads + 4 broadcast p-loads + 16 FMA per iter. No
// shuffles, no exp. 8 units merge via LDS (plain sum).
// ---------------------------------------------------------------------------
__global__ __launch_bounds__(256) void attn_pv_kernel(
    const float* __restrict__ s, const float* __restrict__ v,
    float* __restrict__ py) {
  const int blk = blockIdx.x;                   // bh*NCHUNK + chunk
  const int bh = blk >> 3;
  const int chunk = blk & 7;
  const int lane = threadIdx.x & 63;
  const int wave = threadIdx.x >> 6;
  const int half = lane >> 5;
  const int dl = lane & 31;
  const int unit = wave * 2 + half;

  const float* vp = v + (size_t)bh * T_DIM * HS_DIM;
  const float* sp = s + (size_t)bh * T_DIM;
  const int tbase = chunk * TCHUNK + unit;

  float y0 = 0.f, y1 = 0.f, y2 = 0.f, y3 = 0.f;
#pragma unroll 2
  for (int ti = 0; ti < TCHUNK / 32; ++ti) {    // 16 iters, 4 rows/unit/iter
    const size_t t = tbase + (size_t)ti * 32;
    const float4 v0 = nt_load4(vp + (t +  0) * HS_DIM + dl * 4);
    const float4 v1 = nt_load4(vp + (t +  8) * HS_DIM + dl * 4);
    const float4 v2 = nt_load4(vp + (t + 16) * HS_DIM + dl * 4);
    const float4 v3 = nt_load4(vp + (t + 24) * HS_DIM + dl * 4);
    const float p0 = sp[t + 0];
    const float p1 = sp[t + 8];
    const float p2 = sp[t + 16];
    const float p3 = sp[t + 24];
    y0 = fmaf(p3, v3.x, fmaf(p2, v2.x, fmaf(p1, v1.x, fmaf(p0, v0.x, y0))));
    y1 = fmaf(p3, v3.y, fmaf(p2, v2.y, fmaf(p1, v1.y, fmaf(p0, v0.y, y1))));
    y2 = fmaf(p3, v3.z, fmaf(p2, v2.z, fmaf(p1, v1.z, fmaf(p0, v0.z, y2))));
    y3 = fmaf(p3, v3.w, fmaf(p2, v2.w, fmaf(p1, v1.w, fmaf(p0, v0.w, y3))));
  }

  __shared__ float ly[8 * HS_DIM];
  reinterpret_cast<float4*>(ly)[unit * 32 + dl] = make_float4(y0, y1, y2, y3);
  __syncthreads();
  const int tid = threadIdx.x;
  if (tid < HS_DIM) {
    float acc = 0.f;
#pragma unroll
    for (int u = 0; u < 8; ++u) acc += ly[u * HS_DIM + tid];
    py[(size_t)blk * HS_DIM + tid] = acc;
  }
}

// ---------------------------------------------------------------------------
// Kernel 5: plain-sum NCHUNK partials per (b,h). Grid 256 x 128.
// ---------------------------------------------------------------------------
__global__ __launch_bounds__(128) void attn_combine_kernel(
    const float* __restrict__ py, float* __restrict__ y) {
  const int bh = blockIdx.x;
  const int d = threadIdx.x;
  float acc = 0.f;
#pragma unroll
  for (int c = 0; c < NCHUNK; ++c)
    acc += py[((size_t)bh * NCHUNK + c) * HS_DIM + d];
  y[(size_t)bh * HS_DIM + d] = acc;
}

extern "C" void kernel_launch(void* const* d_in, const int* in_sizes, int n_in,
                              void* d_out, int out_size, void* d_ws, size_t ws_size,
                              hipStream_t stream) {
  const float* x  = (const float*)d_in[0];   // [16, 1, 2048]
  const float* k  = (const float*)d_in[1];   // [16, 16, 4096, 128]
  const float* v  = (const float*)d_in[2];   // [16, 16, 4096, 128]
  const float* Wq = (const float*)d_in[3];   // [2048, 2048]
  const float* Wp = (const float*)d_in[4];   // [2048, 2048]
  float* out = (float*)d_out;                // [16, 1, 2048]

  float* ws    = (float*)d_ws;
  float* q_ws  = ws;                              // [16, 2048]
  float* y_ws  = q_ws + B_DIM * C_DIM;            // [16, 2048]
  float* s_ws  = y_ws + B_DIM * C_DIM;            // [256, 4096]
  float* py_ws = s_ws + (size_t)B_DIM * H_DIM * T_DIM;  // [2048, 128]

  hipLaunchKernelGGL(gemv16_kernel, dim3(C_DIM / 4), dim3(256), 0, stream,
                     x, Wq, q_ws);
  hipLaunchKernelGGL(attn_scores_kernel, dim3(B_DIM * H_DIM * NCHUNK), dim3(256), 0, stream,
                     q_ws, k, s_ws);
  hipLaunchKernelGGL(attn_norm_kernel, dim3(B_DIM * H_DIM), dim3(256), 0, stream,
                     s_ws);
  hipLaunchKernelGGL(attn_pv_kernel, dim3(B_DIM * H_DIM * NCHUNK), dim3(256), 0, stream,
                     s_ws, v, py_ws);
  hipLaunchKernelGGL(attn_combine_kernel, dim3(B_DIM * H_DIM), dim3(128), 0, stream,
                     py_ws, y_ws);
  hipLaunchKernelGGL(gemv16_kernel, dim3(C_DIM / 4), dim3(256), 0, stream,
                     y_ws, Wp, out);
}